// Round 15
// baseline (282.233 us; speedup 1.0000x reference)
//
#include <hip/hip_runtime.h>
#include <hip/hip_fp16.h>

// GCN 3-layer, CSR-gather, low-rank L1 + fused L2/L3 transform.
//   deg+rank atomic histogram (~75us = 1.6M device-scope RMW, floor) + T1 tail ->
//   scan -> fill: ONE int2 (8B) scatter/edge: {src|label<<16, out_norm} ->
//   L1 fused: h1s(fp16) = relu(in_norm*sum w_e*T1[lbl_e] + b1)*out_norm (linear stream)
//   L2 agg:  agg(fp32) = gather(h1s fp16) — ONE 16B load per edge-row per thread
//   L2+L3 fused GEMM (W2/W3 in LDS), t = h2@W3 fp16, stride 64 halfs = 128B,
//     cols 52..63 stored as zeros (free via zero-padded W_s)
//   out = in_norm*gather(t fp16, 7x16B chunks) + b3   [fp32 accumulate everywhere]
#define N_NODES 50000
#define N_EDGES 800000
#define EMB     64
#define HID     96
#define NLAB    50
#define NB_SCAN ((N_NODES + 255) / 256)    // 196
#define TSTRIDE 64                         // t row stride (halfs): 128B line-aligned
#define TCO     7                          // gather chunks over t (7 x 8 halfs = cols 0..55)
#define EDGEB   ((N_EDGES + 255) / 256)    // 3125
#define T1B     ((NLAB * HID + 255) / 256) // 19

__device__ __forceinline__ float2 h2f(unsigned u) {
    __half2 h = *reinterpret_cast<__half2*>(&u);
    return __half22float2(h);
}
__device__ __forceinline__ unsigned f2h(float a, float b) {
    __half2 h = __floats2half2_rn(a, b);
    return *reinterpret_cast<unsigned*>(&h);
}

// Histogram both degrees; rank[i] = old count of dst bucket. Tail blocks (VALU
// idle here - atomic-bound) compute T1 = emb@W1.
__global__ void deg_rank_t1_kernel(const int* __restrict__ src, const int* __restrict__ dst,
                                   int* __restrict__ deg_out, int* __restrict__ deg_in,
                                   int* __restrict__ rank,
                                   const float* __restrict__ emb, const float* __restrict__ W1,
                                   float* __restrict__ T1) {
    int b = blockIdx.x;
    if (b < EDGEB) {
        int i = b * 256 + threadIdx.x;
        if (i < N_EDGES) {
            atomicAdd(&deg_out[src[i]], 1);
            rank[i] = atomicAdd(&deg_in[dst[i]], 1);
        }
    } else {
        int i = (b - EDGEB) * 256 + threadIdx.x;
        if (i < NLAB * HID) {
            int l = i / HID, j = i - l * HID;
            float sum = 0.0f;
#pragma unroll
            for (int k = 0; k < EMB; ++k) sum += emb[l * EMB + k] * W1[k * HID + j];
            T1[i] = sum;
        }
    }
}

// --- block sums of deg_in ---
__global__ void scan1_kernel(const int* __restrict__ deg, int* __restrict__ bsum) {
    __shared__ int s[256];
    int t = threadIdx.x, i = blockIdx.x * 256 + t;
    s[t] = (i < N_NODES) ? deg[i] : 0;
    for (int off = 128; off > 0; off >>= 1) {
        __syncthreads();
        if (t < off) s[t] += s[t + off];
    }
    if (t == 0) bsum[blockIdx.x] = s[0];
}

// Merged scan2+scan3: each block derives its prefix from bsum, scans its chunk,
// and emits norms + node_info (label<<16 in .x, out_norm bits in .y).
__global__ void scan23_kernel(const int* __restrict__ deg_in, const int* __restrict__ bsum,
                              const int* __restrict__ deg_out, const int* __restrict__ labels,
                              int* __restrict__ row_off,
                              float* __restrict__ out_norm, float* __restrict__ in_norm,
                              int2* __restrict__ node_info) {
    __shared__ int pb[256];
    __shared__ int s[256];
    int t = threadIdx.x, i = blockIdx.x * 256 + t;
    pb[t] = (t < (int)blockIdx.x) ? bsum[t] : 0;
    int own = (i < N_NODES) ? deg_in[i] : 0;
    s[t] = own;
    __syncthreads();
    for (int off = 128; off > 0; off >>= 1) {
        if (t < off) pb[t] += pb[t + off];
        __syncthreads();
    }
    int base = pb[0];
    for (int off = 1; off < 256; off <<= 1) {
        int v = s[t];
        if (t >= off) v += s[t - off];
        __syncthreads();
        s[t] = v;
        __syncthreads();
    }
    if (i < N_NODES) {
        row_off[i] = base + s[t] - own;
        float on = rsqrtf(fmaxf((float)deg_out[i], 1.0f));
        out_norm[i] = on;
        in_norm[i]  = rsqrtf(fmaxf((float)own, 1.0f));
        node_info[i] = make_int2(labels[i] << 16, __float_as_int(on));
    }
}

// Atomic-free CSR fill: ONE 8B scatter per edge. rec = {src|label<<16, out_norm}
__global__ void fill_kernel(const int* __restrict__ src, const int* __restrict__ dst,
                            const int* __restrict__ row_off, const int* __restrict__ rank,
                            const int2* __restrict__ node_info,
                            int2* __restrict__ edge_rec) {
    int i = blockIdx.x * blockDim.x + threadIdx.x;
    if (i < N_EDGES) {
        int s = src[i];
        int2 ni = node_info[s];
        int pos = row_off[dst[i]] + rank[i];
        edge_rec[pos] = make_int2(s | ni.x, ni.y);
    }
}

// Fused layer 1: 2 float4 chunks per thread, unroll-4 edges; edge_rec read linearly.
// h1s (FP16) = relu(in_norm*sum w_e*T1[lbl_e] + b1) * out_norm
__global__ void gather1t_kernel(const int2* __restrict__ edge_rec, const float* __restrict__ T1,
                                const int* __restrict__ row_off, const int* __restrict__ deg,
                                const float* __restrict__ in_norm,
                                const float* __restrict__ out_norm, const float* __restrict__ b1,
                                __half* __restrict__ h1s) {
    constexpr int C = HID / 8;   // 12 chunk-pairs per node
    int i = blockIdx.x * blockDim.x + threadIdx.x;
    if (i >= N_NODES * C) return;
    int n = i / C;
    int c = i - n * C;
    const float* t1a = T1 + c * 4;
    const float* t1b = T1 + (c + C) * 4;
    int k = row_off[n];
    int e = k + deg[n];
    float ax = 0.f, ay = 0.f, az = 0.f, aw = 0.f;
    float bx = 0.f, by = 0.f, bz = 0.f, bw = 0.f;
    for (; k + 3 < e; k += 4) {
        int2 i0 = edge_rec[k];
        int2 i1 = edge_rec[k + 1];
        int2 i2 = edge_rec[k + 2];
        int2 i3 = edge_rec[k + 3];
        int r0 = ((unsigned)i0.x >> 16) * HID, r1 = ((unsigned)i1.x >> 16) * HID;
        int r2 = ((unsigned)i2.x >> 16) * HID, r3 = ((unsigned)i3.x >> 16) * HID;
        float4 aA = *(const float4*)(t1a + r0); float4 bA = *(const float4*)(t1b + r0);
        float4 aB = *(const float4*)(t1a + r1); float4 bB = *(const float4*)(t1b + r1);
        float4 aC = *(const float4*)(t1a + r2); float4 bC = *(const float4*)(t1b + r2);
        float4 aD = *(const float4*)(t1a + r3); float4 bD = *(const float4*)(t1b + r3);
        float w0 = __int_as_float(i0.y), w1 = __int_as_float(i1.y);
        float w2 = __int_as_float(i2.y), w3 = __int_as_float(i3.y);
        ax += aA.x * w0 + aB.x * w1 + aC.x * w2 + aD.x * w3;
        ay += aA.y * w0 + aB.y * w1 + aC.y * w2 + aD.y * w3;
        az += aA.z * w0 + aB.z * w1 + aC.z * w2 + aD.z * w3;
        aw += aA.w * w0 + aB.w * w1 + aC.w * w2 + aD.w * w3;
        bx += bA.x * w0 + bB.x * w1 + bC.x * w2 + bD.x * w3;
        by += bA.y * w0 + bB.y * w1 + bC.y * w2 + bD.y * w3;
        bz += bA.z * w0 + bB.z * w1 + bC.z * w2 + bD.z * w3;
        bw += bA.w * w0 + bB.w * w1 + bC.w * w2 + bD.w * w3;
    }
    for (; k < e; ++k) {
        int2 i0 = edge_rec[k];
        int r0 = ((unsigned)i0.x >> 16) * HID;
        float4 aA = *(const float4*)(t1a + r0); float4 bA = *(const float4*)(t1b + r0);
        float w0 = __int_as_float(i0.y);
        ax += aA.x * w0; ay += aA.y * w0; az += aA.z * w0; aw += aA.w * w0;
        bx += bA.x * w0; by += bA.y * w0; bz += bA.z * w0; bw += bA.w * w0;
    }
    float nn = in_norm[n];
    float on = out_norm[n];
    float4 b1a = *(const float4*)(b1 + c * 4);
    float4 b1b = *(const float4*)(b1 + (c + C) * 4);
    uint2 rA, rB;
    rA.x = f2h(fmaxf(ax * nn + b1a.x, 0.f) * on, fmaxf(ay * nn + b1a.y, 0.f) * on);
    rA.y = f2h(fmaxf(az * nn + b1a.z, 0.f) * on, fmaxf(aw * nn + b1a.w, 0.f) * on);
    rB.x = f2h(fmaxf(bx * nn + b1b.x, 0.f) * on, fmaxf(by * nn + b1b.y, 0.f) * on);
    rB.y = f2h(fmaxf(bz * nn + b1b.z, 0.f) * on, fmaxf(bw * nn + b1b.w, 0.f) * on);
    __half* op = h1s + (size_t)n * HID;
    *(uint2*)(op + c * 4) = rA;
    *(uint2*)(op + (c + C) * 4) = rB;
}

// Layer-2 aggregate: ONE uint4 (16B = 8 halfs) load per edge-row per thread.
// C = 12 chunks x 8 halfs; rows 192B = 12x16B aligned. src = edge_rec[k].x & 0xFFFF.
__global__ void gather16_kernel(const __half* __restrict__ hs, const int* __restrict__ row_off,
                                const int* __restrict__ deg, const int2* __restrict__ erec,
                                const float* __restrict__ in_norm, float* __restrict__ out) {
    constexpr int C = HID / 8;   // 12
    int i = blockIdx.x * blockDim.x + threadIdx.x;
    if (i >= N_NODES * C) return;
    int n = i / C;
    int c = i - n * C;
    const __half* p0 = hs + c * 8;
    int k = row_off[n];
    int e = k + deg[n];
    float a0 = 0.f, a1 = 0.f, a2 = 0.f, a3 = 0.f;
    float a4 = 0.f, a5 = 0.f, a6 = 0.f, a7 = 0.f;
    for (; k + 3 < e; k += 4) {
        size_t r0 = (size_t)(erec[k].x & 0xFFFF) * HID;
        size_t r1 = (size_t)(erec[k + 1].x & 0xFFFF) * HID;
        size_t r2 = (size_t)(erec[k + 2].x & 0xFFFF) * HID;
        size_t r3 = (size_t)(erec[k + 3].x & 0xFFFF) * HID;
        uint4 vA = *(const uint4*)(p0 + r0);
        uint4 vB = *(const uint4*)(p0 + r1);
        uint4 vC = *(const uint4*)(p0 + r2);
        uint4 vD = *(const uint4*)(p0 + r3);
        float2 f;
        f = h2f(vA.x); a0 += f.x; a1 += f.y;  f = h2f(vA.y); a2 += f.x; a3 += f.y;
        f = h2f(vA.z); a4 += f.x; a5 += f.y;  f = h2f(vA.w); a6 += f.x; a7 += f.y;
        f = h2f(vB.x); a0 += f.x; a1 += f.y;  f = h2f(vB.y); a2 += f.x; a3 += f.y;
        f = h2f(vB.z); a4 += f.x; a5 += f.y;  f = h2f(vB.w); a6 += f.x; a7 += f.y;
        f = h2f(vC.x); a0 += f.x; a1 += f.y;  f = h2f(vC.y); a2 += f.x; a3 += f.y;
        f = h2f(vC.z); a4 += f.x; a5 += f.y;  f = h2f(vC.w); a6 += f.x; a7 += f.y;
        f = h2f(vD.x); a0 += f.x; a1 += f.y;  f = h2f(vD.y); a2 += f.x; a3 += f.y;
        f = h2f(vD.z); a4 += f.x; a5 += f.y;  f = h2f(vD.w); a6 += f.x; a7 += f.y;
    }
    for (; k < e; ++k) {
        size_t r0 = (size_t)(erec[k].x & 0xFFFF) * HID;
        uint4 vA = *(const uint4*)(p0 + r0);
        float2 f;
        f = h2f(vA.x); a0 += f.x; a1 += f.y;  f = h2f(vA.y); a2 += f.x; a3 += f.y;
        f = h2f(vA.z); a4 += f.x; a5 += f.y;  f = h2f(vA.w); a6 += f.x; a7 += f.y;
    }
    float nn = in_norm[n];
    float4 lo, hi;
    lo.x = a0 * nn; lo.y = a1 * nn; lo.z = a2 * nn; lo.w = a3 * nn;
    hi.x = a4 * nn; hi.y = a5 * nn; hi.z = a6 * nn; hi.w = a7 * nn;
    float* op = out + (size_t)n * HID + c * 8;
    *(float4*)op = lo;
    *(float4*)(op + 4) = hi;
}

// Fused layers 2+3 (LDS-W form): h2 = relu(agg@W2+b2)*out_norm in LDS,
// t = h2@W3 fp16, stride 64 halfs; ALL 64 cols stored (52..63 = 0 via W_s pad).
__global__ __launch_bounds__(256) void linear23_kernel(
        const float* __restrict__ agg, const float* __restrict__ W2,
        const float* __restrict__ b2, const float* __restrict__ out_norm,
        const float* __restrict__ W3, __half* __restrict__ t) {
    constexpr int INP = 100;
    __shared__ float in_s[64][INP];      // 25.6 KB
    __shared__ float W_s[HID * HID];     // 36.9 KB ([k][j]; phase 2: 96x64)
    __shared__ float bs[HID];
    const int tid = threadIdx.x;
    const int n0 = blockIdx.x * 64;

    for (int idx = tid; idx < 64 * (HID / 4); idx += 256) {
        int m = idx / (HID / 4), c = idx - m * (HID / 4);
        int n = n0 + m;
        float4 v = (n < N_NODES) ? *(const float4*)(agg + (size_t)n * HID + c * 4)
                                 : make_float4(0.f, 0.f, 0.f, 0.f);
        *(float4*)(&in_s[m][c * 4]) = v;
    }
    for (int idx = tid; idx < HID * HID / 4; idx += 256)
        *(float4*)(&W_s[idx * 4]) = *(const float4*)(W2 + idx * 4);
    if (tid < HID) bs[tid] = b2[tid];
    __syncthreads();

    const int tx = tid & 15, ty = tid >> 4;
    const int j0 = tx * 6, m0 = ty * 4;

    // GEMM1: 64x96 @ 96x96
    float acc[4][6];
#pragma unroll
    for (int i = 0; i < 4; ++i)
#pragma unroll
        for (int jj = 0; jj < 6; ++jj) acc[i][jj] = 0.0f;
#pragma unroll 4
    for (int k = 0; k < HID; ++k) {
        float a[4], w[6];
#pragma unroll
        for (int i = 0; i < 4; ++i) a[i] = in_s[m0 + i][k];
#pragma unroll
        for (int jj = 0; jj < 6; ++jj) w[jj] = W_s[k * HID + j0 + jj];
#pragma unroll
        for (int i = 0; i < 4; ++i)
#pragma unroll
            for (int jj = 0; jj < 6; ++jj) acc[i][jj] += a[i] * w[jj];
    }
    __syncthreads();

    // h2 tile -> in_s (in place); W3 (zero-padded to 64 cols) -> W_s
#pragma unroll
    for (int i = 0; i < 4; ++i) {
        int n = n0 + m0 + i;
        float on = (n < N_NODES) ? out_norm[n] : 0.0f;
#pragma unroll
        for (int jj = 0; jj < 6; ++jj)
            in_s[m0 + i][j0 + jj] = fmaxf(acc[i][jj] + bs[j0 + jj], 0.0f) * on;
    }
    for (int idx = tid; idx < HID * 64; idx += 256) {
        int k = idx >> 6, j = idx & 63;
        W_s[idx] = (j < NLAB) ? W3[k * NLAB + j] : 0.0f;
    }
    __syncthreads();

    // GEMM2: 64x96 @ 96x64 (cols >= 50 zero -> stored zeros pad the row to 128B)
    const int j20 = tx * 4;
    float acc2[4][4];
#pragma unroll
    for (int i = 0; i < 4; ++i)
#pragma unroll
        for (int jj = 0; jj < 4; ++jj) acc2[i][jj] = 0.0f;
#pragma unroll 4
    for (int k = 0; k < HID; ++k) {
        float a[4], w[4];
#pragma unroll
        for (int i = 0; i < 4; ++i) a[i] = in_s[m0 + i][k];
#pragma unroll
        for (int jj = 0; jj < 4; ++jj) w[jj] = W_s[k * 64 + j20 + jj];
#pragma unroll
        for (int i = 0; i < 4; ++i)
#pragma unroll
            for (int jj = 0; jj < 4; ++jj) acc2[i][jj] += a[i] * w[jj];
    }
#pragma unroll
    for (int i = 0; i < 4; ++i) {
        int n = n0 + m0 + i;
        if (n >= N_NODES) break;
        uint2 raw;
        raw.x = f2h(acc2[i][0], acc2[i][1]);
        raw.y = f2h(acc2[i][2], acc2[i][3]);
        *(uint2*)(t + (size_t)n * TSTRIDE + j20) = raw;
    }
}

// Final gather over FP16 t (128B rows): 7 chunks x 8 halfs (cols 0..55; 52+ zero).
__global__ void gather_out_kernel(const __half* __restrict__ t, const int* __restrict__ row_off,
                                  const int* __restrict__ deg, const int2* __restrict__ erec,
                                  const float* __restrict__ in_norm, const float* __restrict__ bias,
                                  float* __restrict__ out) {
    int i = blockIdx.x * blockDim.x + threadIdx.x;
    if (i >= N_NODES * TCO) return;
    int n = i / TCO;
    int c = i - n * TCO;
    const __half* p0 = t + c * 8;
    int k = row_off[n];
    int e = k + deg[n];
    float a0 = 0.f, a1 = 0.f, a2 = 0.f, a3 = 0.f;
    float a4 = 0.f, a5 = 0.f, a6 = 0.f, a7 = 0.f;
    for (; k + 3 < e; k += 4) {
        size_t r0 = (size_t)(erec[k].x & 0xFFFF) * TSTRIDE;
        size_t r1 = (size_t)(erec[k + 1].x & 0xFFFF) * TSTRIDE;
        size_t r2 = (size_t)(erec[k + 2].x & 0xFFFF) * TSTRIDE;
        size_t r3 = (size_t)(erec[k + 3].x & 0xFFFF) * TSTRIDE;
        uint4 vA = *(const uint4*)(p0 + r0);
        uint4 vB = *(const uint4*)(p0 + r1);
        uint4 vC = *(const uint4*)(p0 + r2);
        uint4 vD = *(const uint4*)(p0 + r3);
        float2 f;
        f = h2f(vA.x); a0 += f.x; a1 += f.y;  f = h2f(vA.y); a2 += f.x; a3 += f.y;
        f = h2f(vA.z); a4 += f.x; a5 += f.y;  f = h2f(vA.w); a6 += f.x; a7 += f.y;
        f = h2f(vB.x); a0 += f.x; a1 += f.y;  f = h2f(vB.y); a2 += f.x; a3 += f.y;
        f = h2f(vB.z); a4 += f.x; a5 += f.y;  f = h2f(vB.w); a6 += f.x; a7 += f.y;
        f = h2f(vC.x); a0 += f.x; a1 += f.y;  f = h2f(vC.y); a2 += f.x; a3 += f.y;
        f = h2f(vC.z); a4 += f.x; a5 += f.y;  f = h2f(vC.w); a6 += f.x; a7 += f.y;
        f = h2f(vD.x); a0 += f.x; a1 += f.y;  f = h2f(vD.y); a2 += f.x; a3 += f.y;
        f = h2f(vD.z); a4 += f.x; a5 += f.y;  f = h2f(vD.w); a6 += f.x; a7 += f.y;
    }
    for (; k < e; ++k) {
        size_t r0 = (size_t)(erec[k].x & 0xFFFF) * TSTRIDE;
        uint4 vA = *(const uint4*)(p0 + r0);
        float2 f;
        f = h2f(vA.x); a0 += f.x; a1 += f.y;  f = h2f(vA.y); a2 += f.x; a3 += f.y;
        f = h2f(vA.z); a4 += f.x; a5 += f.y;  f = h2f(vA.w); a6 += f.x; a7 += f.y;
    }
    float nn = in_norm[n];
    int j = c * 8;
    float* op = out + (size_t)n * NLAB + j;   // rows 8B-aligned -> float2 stores
    float2 v;
    v.x = a0 * nn + bias[j];     v.y = a1 * nn + bias[j + 1];
    *(float2*)op = v;
    if (j + 2 < NLAB) {
        v.x = a2 * nn + bias[j + 2]; v.y = a3 * nn + bias[j + 3];
        *(float2*)(op + 2) = v;
    }
    if (j + 4 < NLAB) {
        v.x = a4 * nn + bias[j + 4]; v.y = a5 * nn + bias[j + 5];
        *(float2*)(op + 4) = v;
        v.x = a6 * nn + bias[j + 6]; v.y = a7 * nn + bias[j + 7];
        *(float2*)(op + 6) = v;
    }
}

static inline int cdiv(long a, int b) { return (int)((a + b - 1) / b); }

extern "C" void kernel_launch(void* const* d_in, const int* in_sizes, int n_in,
                              void* d_out, int out_size, void* d_ws, size_t ws_size,
                              hipStream_t stream) {
    const int*   dep_labels = (const int*)d_in[0];
    const int*   src        = (const int*)d_in[1];
    const int*   dst        = (const int*)d_in[2];
    const float* emb        = (const float*)d_in[3];
    const float* W1 = (const float*)d_in[4]; const float* b1 = (const float*)d_in[5];
    const float* W2 = (const float*)d_in[6]; const float* b2 = (const float*)d_in[7];
    const float* W3 = (const float*)d_in[8]; const float* b3 = (const float*)d_in[9];
    float* out = (float*)d_out;

    // ---- workspace layout (regions kept 128B-aligned) ----
    int* wsp        = (int*)d_ws;
    int* deg_out_i  = wsp;                 wsp += N_NODES;
    int* deg_in_i   = wsp;                 wsp += N_NODES;
    int* row_off    = wsp;                 wsp += N_NODES;
    int* rank       = wsp;                 wsp += N_EDGES;
    int* bsum       = wsp;                 wsp += 256;
    float* out_norm = (float*)wsp;         wsp += N_NODES;
    float* in_norm  = (float*)wsp;         wsp += N_NODES;
    int2* node_info = (int2*)wsp;          wsp += 2 * N_NODES;
    float* T1       = (float*)wsp;         wsp += NLAB * HID + 16;
    int2* edge_rec  = (int2*)wsp;          wsp += 2 * N_EDGES;      // 6.4 MB
    float* bufA     = (float*)wsp;         wsp += (size_t)N_NODES * HID;   // agg (fp32)
    __half* bufH    = (__half*)wsp;        // h1s (fp16), then t (fp16, stride 64)

    const int B = 256;
    const int NLIN = cdiv(N_NODES, 64);    // 782

    hipMemsetAsync(deg_out_i, 0, 2 * N_NODES * sizeof(int), stream);
    deg_rank_t1_kernel<<<EDGEB + T1B, B, 0, stream>>>(src, dst, deg_out_i, deg_in_i, rank,
                                                      emb, W1, T1);

    scan1_kernel<<<NB_SCAN, 256, 0, stream>>>(deg_in_i, bsum);
    scan23_kernel<<<NB_SCAN, 256, 0, stream>>>(deg_in_i, bsum, deg_out_i, dep_labels,
                                               row_off, out_norm, in_norm, node_info);
    fill_kernel<<<EDGEB, B, 0, stream>>>(src, dst, row_off, rank, node_info, edge_rec);

    // Layer 1 fused: linear edge_rec stream, T1 L1-resident -> h1s (fp16)
    gather1t_kernel<<<cdiv((long)N_NODES * (HID / 8), B), B, 0, stream>>>(
        edge_rec, T1, row_off, deg_in_i, in_norm, out_norm, b1, bufH);

    // Layer 2 aggregate (fp16 rows, one 16B load per edge-row per thread)
    gather16_kernel<<<cdiv((long)N_NODES * (HID / 8), B), B, 0, stream>>>(
        bufH, row_off, deg_in_i, edge_rec, in_norm, bufA);

    // Layers 2+3 fused transform: agg -> t (fp16 stride 64; h2 stays in LDS)
    linear23_kernel<<<NLIN, 256, 0, stream>>>(bufA, W2, b2, out_norm, W3, bufH);

    // Final gather + bias (fp16 t -> fp32 out, 7x16B chunks)
    gather_out_kernel<<<cdiv((long)N_NODES * TCO, B), B, 0, stream>>>(
        bufH, row_off, deg_in_i, edge_rec, in_norm, b3, out);
}